// Round 1
// 367.067 us; speedup vs baseline: 1.0066x; 1.0066x over previous
//
#include <hip/hip_runtime.h>

#define BATCH 8192
#define FEATURE_NUM 200
#define NUMERIC_SIZE 100
#define IN_STRIDE (FEATURE_NUM + NUMERIC_SIZE)  // 300
#define EMBED 64
#define WAVES_PER_BLOCK 4

// One wave (64 lanes) per batch row.
// Second-order gather restructure vs previous version:
//   - 16 lanes x float4 cover one 256B embedding row -> 4 rows per
//     global_load_dwordx4 instruction (was 1 row per global_load_dword).
//   - lane group g = lane>>4 handles features {8c+2g, 8c+2g+1}; the two
//     indices are adjacent in LDS so one ds_read_b64 feeds both loads
//     (was 8 scalar ds_read broadcasts per 8 features).
//   - triple-buffered pipeline keeps 4-6 KB of gather bytes in flight per
//     wave (was 2-4 KB), never draining vmcnt in the steady state.
// Each lane accumulates dims e=(lane&15)*4+d; groups are folded with two
// shfl_xor steps before the FM identity. VGPR budget target: <=64 so
// 8 waves/SIMD residency holds (8192 waves == device capacity).

#define LOADC(B0, B1, c) do {                                              \
    int2 ff = *(const int2*)(sidx + 8*(c) + 2*g);                          \
    B0 = *(const float4*)(v_one_hot + (unsigned)ff.x * 64u + sub4);        \
    B1 = *(const float4*)(v_one_hot + (unsigned)ff.y * 64u + sub4);        \
} while (0)

#define ACCUM(B0, B1) do {                                                 \
    fs0 += B0.x; fss0 += B0.x * B0.x;                                      \
    fs1 += B0.y; fss1 += B0.y * B0.y;                                      \
    fs2 += B0.z; fss2 += B0.z * B0.z;                                      \
    fs3 += B0.w; fss3 += B0.w * B0.w;                                      \
    fs0 += B1.x; fss0 += B1.x * B1.x;                                      \
    fs1 += B1.y; fss1 += B1.y * B1.y;                                      \
    fs2 += B1.z; fss2 += B1.z * B1.z;                                      \
    fs3 += B1.w; fss3 += B1.w * B1.w;                                      \
} while (0)

__global__ __launch_bounds__(256, 8) void fm_layer_kernel(
    const float* __restrict__ inputs,      // (B, 300)
    const float* __restrict__ w_one_hot,   // (1e6, 1)
    const float* __restrict__ w_numeric,   // (100, 1)
    const float* __restrict__ v_one_hot,   // (1e6, 64)
    const float* __restrict__ v_numeric,   // (100, 64)
    const float* __restrict__ bias,        // (1,)
    float* __restrict__ out)               // (B, 1)
{
    __shared__ int   s_idx[WAVES_PER_BLOCK][FEATURE_NUM];
    __shared__ float s_num[WAVES_PER_BLOCK][NUMERIC_SIZE];

    const int lane = threadIdx.x & 63;
    const int wave = threadIdx.x >> 6;
    const int row  = blockIdx.x * WAVES_PER_BLOCK + wave;
    const int g    = lane >> 4;                 // 4 lane-groups
    const unsigned sub4 = (unsigned)(lane & 15) * 4u;  // dim base for float4

    const float* in_row = inputs + (size_t)row * IN_STRIDE;

    // coalesced preload of this row's 300 floats; indices converted once
    for (int j = lane; j < IN_STRIDE; j += 64) {
        float x = in_row[j];
        if (j < FEATURE_NUM) s_idx[wave][j] = (int)x;
        else                 s_num[wave][j - FEATURE_NUM] = x;
    }
    __syncthreads();

    const int* sidx = s_idx[wave];
    const float* snum = s_num[wave];

    // ---- first-order gathers: issue EARLY, consume at the end ----
    float w0 = w_one_hot[sidx[lane]];
    float w1 = w_one_hot[sidx[lane + 64]];
    float w2 = w_one_hot[sidx[lane + 128]];
    float w3 = w_one_hot[sidx[192 + (lane & 7)]];   // only lanes 0-7 count

    float fs0 = 0.f, fs1 = 0.f, fs2 = 0.f, fs3 = 0.f;
    float fss0 = 0.f, fss1 = 0.f, fss2 = 0.f, fss3 = 0.f;

    float4 va0, va1, vb0, vb1, vc0, vc1;

    // prologue: chunks 0,1 in flight
    LOADC(va0, va1, 0);
    LOADC(vb0, vb1, 1);

    // ---- numeric second-order (v_numeric 25.6 KB, L1-resident) ----
    // group g handles numeric features f = 4t+g; overlaps chunk-0/1 latency
    #pragma unroll 5
    for (int t = 0; t < 25; ++t) {
        int f = 4 * t + g;
        float x = snum[f];
        float4 v = *(const float4*)(v_numeric + (unsigned)f * 64u + sub4);
        float n0 = x * v.x; fs0 += n0; fss0 += n0 * n0;
        float n1 = x * v.y; fs1 += n1; fss1 += n1 * n1;
        float n2 = x * v.z; fs2 += n2; fss2 += n2 * n2;
        float n3 = x * v.w; fs3 += n3; fss3 += n3 * n3;
    }

    // ---- main pipeline: 25 chunks of 8 features, triple-buffered ----
    #pragma unroll 1
    for (int t = 0; t < 7; ++t) {
        int c = 3 * t;
        LOADC(vc0, vc1, c + 2); ACCUM(va0, va1);   // accum chunk 3t
        LOADC(va0, va1, c + 3); ACCUM(vb0, vb1);   // accum chunk 3t+1
        LOADC(vb0, vb1, c + 4); ACCUM(vc0, vc1);   // accum chunk 3t+2
    }
    // after loop: va=21, vb=22; chunks 23,24 not yet loaded
    LOADC(vc0, vc1, 23); ACCUM(va0, va1);          // 21
    LOADC(va0, va1, 24); ACCUM(vb0, vb1);          // 22
    ACCUM(vc0, vc1);                               // 23
    ACCUM(va0, va1);                               // 24

    // ---- fold the 4 lane-groups: lanes sub, sub+16, sub+32, sub+48 hold
    // partials for the same 4 dims ----
    #define XRED(v) v += __shfl_xor(v, 16, 64); v += __shfl_xor(v, 32, 64)
    XRED(fs0); XRED(fs1); XRED(fs2); XRED(fs3);
    XRED(fss0); XRED(fss1); XRED(fss2); XRED(fss3);
    #undef XRED

    // ---- first-order combine ----
    float first = w0 + w1 + w2 + ((lane < 8) ? w3 : 0.f);
    first += snum[lane] * w_numeric[lane];
    if (lane < NUMERIC_SIZE - 64) first += snum[lane + 64] * w_numeric[lane + 64];

    // FM identity for this lane's 4 dims; count group 0 only (groups are
    // identical copies after the xor-fold)
    float so = (fs0 * fs0 - fss0) + (fs1 * fs1 - fss1)
             + (fs2 * fs2 - fss2) + (fs3 * fs3 - fss3);
    float partial = first + ((g == 0) ? 0.5f * so : 0.f);

    // wave64 reduction
    #pragma unroll
    for (int off = 32; off > 0; off >>= 1)
        partial += __shfl_down(partial, off, 64);

    if (lane == 0) out[row] = partial + bias[0];
}

extern "C" void kernel_launch(void* const* d_in, const int* in_sizes, int n_in,
                              void* d_out, int out_size, void* d_ws, size_t ws_size,
                              hipStream_t stream) {
    const float* inputs    = (const float*)d_in[0];
    const float* w_one_hot = (const float*)d_in[1];
    const float* w_numeric = (const float*)d_in[2];
    const float* v_one_hot = (const float*)d_in[3];
    const float* v_numeric = (const float*)d_in[4];
    const float* bias      = (const float*)d_in[5];
    float* out = (float*)d_out;

    dim3 grid(BATCH / WAVES_PER_BLOCK);
    dim3 block(256);
    fm_layer_kernel<<<grid, block, 0, stream>>>(
        inputs, w_one_hot, w_numeric, v_one_hot, v_numeric, bias, out);
}